// Round 9
// baseline (261.560 us; speedup 1.0000x reference)
//
#include <hip/hip_runtime.h>
#include <hip/hip_bf16.h>

// Problem constants
#define B_    32
#define C_    256     // Cin == Cout
#define H_    56
#define W_    56
#define HP    58      // padded H
#define WPAD  58      // padded W
#define HW    3136    // H_*W_
#define CHW   802816  // C_*H_*W_
#define M_TOT 100352  // B_*H_*W_

typedef int intx4 __attribute__((ext_vector_type(4)));

#define XPAD_BYTES (B_ * HP * WPAD * C_)        // 27,557,888 (i8)
#define WPK_BYTES  (C_ * 9 * C_)                // 589,824 (i8)

__device__ __forceinline__ int sgn8(float f) {
  return ((f > 0.f) ? 1 : ((f < 0.f) ? -1 : 0)) & 0xff;
}

// ---------------------------------------------------------------------------
// Merged pack kernel: blocks [0, B_*HP) run the pack_x role (sign(x) NCHW
// fp32 -> padded NHWC i8), blocks [B_*HP, B_*HP+C_) run the pack_w role
// (wq[co][s][ci] i8 = sign(w1)+sign(w2), alphah[co]). Validated R3-R7:
// saves ~4 us vs separate launches, results identical.
// ---------------------------------------------------------------------------
#define ROWPC 272
__global__ __launch_bounds__(256) void pack_kernel(const float* __restrict__ in,
                                                   const float* __restrict__ w1,
                                                   const float* __restrict__ w2,
                                                   char* __restrict__ xp,
                                                   char* __restrict__ wq,
                                                   float* __restrict__ alphah) {
  __shared__ char smem[18448];
  const int tid = threadIdx.x;

  if (blockIdx.x < B_ * HP) {
    // ---------------- pack_x role ----------------
    char* row = smem;   // 58 * ROWPC = 15776 B
    const int yp = blockIdx.x % HP;
    const int b  = blockIdx.x / HP;

    float4* rz = (float4*)row;
    const float4 z4 = make_float4(0.f, 0.f, 0.f, 0.f);
#pragma unroll
    for (int i = 0; i < 4; ++i) {
      const int idx = i * 256 + tid;
      if (idx < (58 * ROWPC) / 16) rz[idx] = z4;
    }
    __syncthreads();

    const int y = yp - 1;
    const int xq = tid % 14;   // x quad: x = xq*4 .. xq*4+3
    const int cs = tid / 14;   // ci-quad slot 0..18 (252..255 idle)
    if (y >= 0 && y < H_ && cs < 18) {
      const float* base = in + ((size_t)b * C_ * H_ + (size_t)y) * W_ + xq * 4;
#pragma unroll
      for (int k = 0; k < 4; ++k) {
        const int cq = cs + 18 * k;          // ci quad index 0..63
        if (cq < 64) {
          float4 f[4];
#pragma unroll
          for (int j = 0; j < 4; ++j)
            f[j] = *(const float4*)(base + (size_t)(cq * 4 + j) * (H_ * W_));
#pragma unroll
          for (int d = 0; d < 4; ++d) {
            const float v0 = (d == 0) ? f[0].x : (d == 1) ? f[0].y : (d == 2) ? f[0].z : f[0].w;
            const float v1 = (d == 0) ? f[1].x : (d == 1) ? f[1].y : (d == 2) ? f[1].z : f[1].w;
            const float v2 = (d == 0) ? f[2].x : (d == 1) ? f[2].y : (d == 2) ? f[2].z : f[2].w;
            const float v3 = (d == 0) ? f[3].x : (d == 1) ? f[3].y : (d == 2) ? f[3].z : f[3].w;
            const unsigned int pk = (unsigned)sgn8(v0) | ((unsigned)sgn8(v1) << 8) |
                                    ((unsigned)sgn8(v2) << 16) | ((unsigned)sgn8(v3) << 24);
            *(unsigned int*)&row[(xq * 4 + d + 1) * ROWPC + cq * 4] = pk;
          }
        }
      }
    }
    __syncthreads();

    const int cc = tid & 15;   // 16 chunks = full 256 B ci-row
    const int xo = tid >> 4;   // 16 x per iter
    char* dst = xp + (size_t)(b * HP + yp) * WPAD * C_;
#pragma unroll
    for (int it = 0; it < 4; ++it) {
      const int xs = it * 16 + xo;
      if (xs < WPAD)
        *(float4*)(dst + xs * C_ + cc * 16) = *(const float4*)&row[xs * ROWPC + cc * 16];
    }
  } else {
    // ---------------- pack_w role ----------------
    float* l1 = (float*)smem;          // 2304 f
    float* l2 = l1 + 2304;             // 2304 f
    float* red = (float*)(smem + 18432);  // 4 f
    const int co = blockIdx.x - B_ * HP;
    const float* s1 = w1 + co * 2304;
    const float* s2 = w2 + co * 2304;
#pragma unroll
    for (int i = 0; i < 9; ++i) {       // stride-1 across lanes: coalesced
      l1[i * 256 + tid] = s1[i * 256 + tid];
      l2[i * 256 + tid] = s2[i * 256 + tid];
    }
    __syncthreads();
    const int ci = tid;
    float sabs = 0.f;
#pragma unroll
    for (int s = 0; s < 9; ++s) {       // LDS stride 9 (odd) -> bank-spread
      const float a = l1[ci * 9 + s];
      const float b = l2[ci * 9 + s];
      const int sa = (a > 0.f) - (a < 0.f);
      const int sb = (b > 0.f) - (b < 0.f);
      wq[(co * 9 + s) * C_ + ci] = (char)(sa + sb);   // coalesced byte store
      sabs += fabsf(a) + fabsf(b);
    }
#pragma unroll
    for (int off = 32; off > 0; off >>= 1) sabs += __shfl_down(sabs, off, 64);
    if ((tid & 63) == 0) red[tid >> 6] = sabs;
    __syncthreads();
    if (tid == 0)
      alphah[co] = (red[0] + red[1] + red[2] + red[3]) * (0.5f / 2304.0f);
  }
}

// ---------------------------------------------------------------------------
// Implicit-GEMM conv, int8, DEPTH-3 COUNTED-VMCNT on the proven residency:
// tile 128(co) x 128(m), 256 thr / 4 waves of 64x64 (R0 wave grid + epilogue
// verbatim), BK=64 -> 36 K-steps, 3 LDS buffers (48 KB total).
// Per step: s_waitcnt vmcnt(4) (retires own stage(t) share; barrier-complete
// => ALL waves' shares landed) -> raw s_barrier -> issue stage(t+2) into the
// buffer freed at step t-1 -> 8 ds_read_b128 -> 16 MFMA. No vmcnt(0) drain
// in the main loop (T4): the R0 structure's ~1100 cyc/step residual.
// Ledger (induction): at iter-t wait, outstanding subset of {stage(t),
// stage(t+1)} = 8 gll -> vmcnt(4) retires stage(t). Tail peeled: t=33
// stages 35, t=34 no stage (vmcnt 4), t=35 vmcnt(0).
// Loop manually unrolled x3: all buffer bases compile-time (R6 lesson).
// Swizzle = R3's 64B-row pattern, harness-verified (absmax 0, conflicts 0).
// __launch_bounds__(256,2): no reg cap (R4 lesson); ~90-110 VGPR, no spill.
// R8 resubmission: bench infra failed twice (no kernel verdict); OOB audit
// (weight/input addresses close exactly at buffer ends), deadlock audit
// (uniform barriers, ledger closes), WAR audit (reads consumed before
// barrier) all clean -- rerunning the identical experiment.
// ---------------------------------------------------------------------------
#define GLL16(src, dst)                                                        \
  __builtin_amdgcn_global_load_lds(                                            \
      (const __attribute__((address_space(1))) void*)(src),                    \
      (__attribute__((address_space(3))) void*)(dst), 16, 0, 0)

__global__ __launch_bounds__(256, 2) void gemm_kernel(const char* __restrict__ xp,
                                                      const char* __restrict__ wq,
                                                      const float* __restrict__ alphah,
                                                      float* __restrict__ out) {
  __shared__ char sA[3 * 128 * 64];   // 24 KB: [buf][co 128][64B]
  __shared__ char sB[3 * 128 * 64];   // 24 KB: [buf][m 128][64B]
  const int tid = threadIdx.x;

  // XCD-paired decode (1568 = 8*196, bijective): blocks id, id+8 are the two
  // co-halves of one m-tile -> B rows shared within one XCD's L2.
  const int id = blockIdx.x;
  const int xcd = id & 7;
  const int l = id >> 3;
  const int co0 = (l & 1) * 128;
  const int m0 = ((l >> 1) * 8 + xcd) * 128;

  // ---- staging geometry (R3-verified): row = tid>>2, chunk = tid&3 ----
  // LDS chunk c of row r holds global chunk c ^ ((r>>1)&3)  (inverse-swz src)
  const int srow = tid >> 2;                        // 0..63
  const int scol = (tid & 3) ^ ((tid >> 3) & 3);    // pre-swizzled src chunk

  const char* wsrc[2];
  const char* xsrc[2];
#pragma unroll
  for (int i = 0; i < 2; ++i) {
    wsrc[i] = wq + (co0 + srow + 64 * i) * 2304 + scol * 16;
    const int m = m0 + srow + 64 * i;
    const int b = m / HW;
    const int rem = m - b * HW;
    const int y = rem / W_;
    const int x = rem - y * W_;
    xsrc[i] = xp + ((b * HP + y) * WPAD + x) * C_ + scol * 16;
  }

  // stage K-step s (tap = s>>2, ci-quarter q = s&3): 4 gll/thread (A 8KB + B 8KB)
  auto stage = [&](int s, char* dA, char* dB) {
    const int tap = s >> 2;
    const int q = s & 3;
    const int woff = tap * 256 + q * 64;
    const int shoff = ((tap / 3) * WPAD + (tap % 3)) * C_ + q * 64;
    GLL16(wsrc[0] + woff, dA);
    GLL16(wsrc[1] + woff, dA + 4096);
    GLL16(xsrc[0] + shoff, dB);
    GLL16(xsrc[1] + shoff, dB + 4096);
  };

  // ---- read-side lane geometry (R0 wave grid) ----
  const int lane = tid & 63;
  const int wave = tid >> 6;
  const int wm = wave >> 1;       // co 64-half
  const int wn = wave & 1;        // m 64-half
  const int lrow = lane & 15;
  const int kq = lane >> 4;       // 16B k-chunk within K=64
  const int coff = (kq ^ ((lrow >> 1) & 3)) * 16;   // swizzled chunk (R3)
  const int abase = (wm * 64 + lrow) * 64 + coff;   // + ii*1024
  const int bbase = (wn * 64 + lrow) * 64 + coff;   // + j*1024

  intx4 acc[4][4] = {};

// One K-step: counted wait, barrier, prefetch 2 ahead, compute buf CBUF.
#define STEP(T, CBUF, SBUF, VM, DOSTAGE)                                       \
  do {                                                                         \
    asm volatile("s_waitcnt vmcnt(" #VM ")" ::: "memory");                     \
    __builtin_amdgcn_s_barrier();                                              \
    asm volatile("" ::: "memory");                                             \
    if (DOSTAGE)                                                               \
      stage((T) + 2, sA + (SBUF) * 8192 + tid * 16,                            \
            sB + (SBUF) * 8192 + tid * 16);                                    \
    const char* bA = sA + (CBUF) * 8192;                                       \
    const char* bB = sB + (CBUF) * 8192;                                       \
    intx4 af[4], bv[4];                                                        \
    _Pragma("unroll")                                                          \
    for (int ii = 0; ii < 4; ++ii)                                             \
      af[ii] = *(const intx4*)(bA + abase + ii * 1024);                        \
    _Pragma("unroll")                                                          \
    for (int j = 0; j < 4; ++j)                                                \
      bv[j] = *(const intx4*)(bB + bbase + j * 1024);                          \
    _Pragma("unroll")                                                          \
    for (int ii = 0; ii < 4; ++ii)                                             \
      _Pragma("unroll")                                                        \
      for (int j = 0; j < 4; ++j)                                              \
        acc[ii][j] = __builtin_amdgcn_mfma_i32_16x16x64_i8(af[ii], bv[j],      \
                                                           acc[ii][j], 0, 0, 0); \
  } while (0)

  // prologue: fill buffers 0,1 (order pinned for vmcnt counting)
  stage(0, sA + tid * 16, sB + tid * 16);
  asm volatile("" ::: "memory");
  stage(1, sA + 8192 + tid * 16, sB + 8192 + tid * 16);

  for (int it = 0; it < 11; ++it) {     // t = 0..32
    const int t = it * 3;
    STEP(t, 0, 2, 4, 1);
    STEP(t + 1, 1, 0, 4, 1);
    STEP(t + 2, 2, 1, 4, 1);
  }
  STEP(33, 0, 2, 4, 1);   // stages 35 -> buf 2
  STEP(34, 1, 0, 4, 0);   // no stage; retires stage(34)
  STEP(35, 2, 1, 0, 0);   // final: drain stage(35)
#undef STEP

  // ---- epilogue (R0 verbatim): D row (kq*4+r) = co, D col (lane&15) = m ----
  int ob[4];
#pragma unroll
  for (int j = 0; j < 4; ++j) {
    const int m = m0 + wn * 64 + j * 16 + lrow;
    const int b = m / HW;
    const int rem = m - b * HW;
    const int y = rem / W_;
    const int x = rem - y * W_;
    ob[j] = b * CHW + y * W_ + x;
  }
#pragma unroll
  for (int ii = 0; ii < 4; ++ii) {
#pragma unroll
    for (int r = 0; r < 4; ++r) {
      const int co = co0 + wm * 64 + ii * 16 + kq * 4 + r;
      const float sc = alphah[co];
#pragma unroll
      for (int j = 0; j < 4; ++j)
        out[ob[j] + co * HW] = (float)acc[ii][j][r] * sc;
    }
  }
}

// ---------------------------------------------------------------------------
extern "C" void kernel_launch(void* const* d_in, const int* in_sizes, int n_in,
                              void* d_out, int out_size, void* d_ws, size_t ws_size,
                              hipStream_t stream) {
  const float* input = (const float*)d_in[0];
  const float* w1 = (const float*)d_in[1];
  const float* w2 = (const float*)d_in[2];
  float* out = (float*)d_out;

  char* ws = (char*)d_ws;
  char* xp = ws;                                    // 27,557,888 B
  char* wq = ws + XPAD_BYTES;                       // 589,824 B
  float* alphah = (float*)(ws + XPAD_BYTES + WPK_BYTES);  // 1,024 B

  pack_kernel<<<B_ * HP + C_, 256, 0, stream>>>(input, w1, w2, xp, wq, alphah);
  gemm_kernel<<<M_TOT / 128 * (C_ / 128), 256, 0, stream>>>(xp, wq, alphah, out);
}